// Round 3
// baseline (44.007 us; speedup 1.0000x reference)
//
#include <hip/hip_runtime.h>
#include <hip/hip_bf16.h>
#include <stdint.h>

#define D_DIM 256
#define K_CTR 1024
#define B_ROWS 16384
#define BM 32
#define CSPLIT 2   // each block: 32 rows x 512 cols

typedef __bf16 bf16x8 __attribute__((ext_vector_type(8)));
typedef float f32x4 __attribute__((ext_vector_type(4)));

static __device__ __forceinline__ unsigned short f2bf(float f) {
    return __builtin_bit_cast(unsigned short, __float2bfloat16(f));
}

// Prep: centers f32 -> bf16 fragment-major + c_sq f32.
// Chunk for (colgrp, kk, hk, col&15) at byte colgrp*8192 + kk*1024 + hk*256 + (col&15)*16,
// so a wave B-load (lane l) is one contiguous 1KB dwordx4 at l*16.
__global__ __launch_bounds__(256) void rbf_prep(const float* __restrict__ centers,
                                                unsigned short* __restrict__ cbf,
                                                float* __restrict__ csq) {
    const int w = threadIdx.x >> 6;
    const int l = threadIdx.x & 63;
    const int base = blockIdx.x * 8;
    #pragma unroll
    for (int i = 0; i < 2; ++i) {
        const int row = base + i * 4 + w;
        const float4 v = *reinterpret_cast<const float4*>(centers + row * D_DIM + l * 4);
        float s = v.x * v.x + v.y * v.y + v.z * v.z + v.w * v.w;
        ushort4 p;
        p.x = f2bf(v.x); p.y = f2bf(v.y); p.z = f2bf(v.z); p.w = f2bf(v.w);
        char* dst = reinterpret_cast<char*>(cbf)
                  + (row >> 4) * 8192 + (l >> 3) * 1024 + ((l >> 1) & 3) * 256
                  + (row & 15) * 16 + (l & 1) * 8;
        *reinterpret_cast<ushort4*>(dst) = p;
        #pragma unroll
        for (int off = 1; off < 64; off <<= 1) s += __shfl_xor(s, off);
        if (l == 0) csq[row] = s;
    }
}

__global__ __launch_bounds__(256) void rbf_main(const float* __restrict__ x,
                                                const unsigned short* __restrict__ cbf,
                                                const float* __restrict__ csq,
                                                const float* __restrict__ betas,
                                                float* __restrict__ out) {
    __shared__ __align__(16) unsigned short As[BM * D_DIM];  // 16 KB, swizzled
    __shared__ float xs_lds[BM];

    const int tid = threadIdx.x;
    const int w = tid >> 6;
    const int l = tid & 63;
    const int bid = blockIdx.x;
    const int strip = bid & (B_ROWS / BM - 1);
    const int cidx  = bid >> 9;
    const int row0 = strip * BM;

    // ---- Stage A strip into LDS (bf16, XOR-swizzled), compute x_sq ----
    #pragma unroll
    for (int i = 0; i < 8; ++i) {
        const int r = i * 4 + w;
        const float4 v = *reinterpret_cast<const float4*>(x + (row0 + r) * D_DIM + l * 4);
        float s = v.x * v.x + v.y * v.y + v.z * v.z + v.w * v.w;
        ushort4 p;
        p.x = f2bf(v.x); p.y = f2bf(v.y); p.z = f2bf(v.z); p.w = f2bf(v.w);
        const unsigned boff = (unsigned)((r * 512 + l * 8) ^ ((r & 7) << 4));
        *reinterpret_cast<ushort4*>(reinterpret_cast<char*>(As) + boff) = p;
        #pragma unroll
        for (int off = 1; off < 64; off <<= 1) s += __shfl_xor(s, off);
        if (l == 0) xs_lds[r] = s;
    }
    __syncthreads();

    const int hk = l >> 4;
    const int lr = l & 15;

    // ---- Hoist ALL A fragments to registers (64 VGPR); no LDS in main loop ----
    bf16x8 a[2][8];
    #pragma unroll
    for (int m = 0; m < 2; ++m) {
        const int r = m * 16 + lr;
        #pragma unroll
        for (int kk = 0; kk < 8; ++kk) {
            const unsigned boff = (unsigned)((r * 512 + kk * 64 + hk * 16) ^ ((r & 7) << 4));
            a[m][kk] = *reinterpret_cast<const bf16x8*>(reinterpret_cast<const char*>(As) + boff);
        }
    }
    const float xsq0 = xs_lds[lr];
    const float xsq1 = xs_lds[16 + lr];

    // ---- 4 column tiles of 128 cols; burst-load B, MFMA, fused epilogue ----
    #pragma unroll 1
    for (int ct = 0; ct < 4; ++ct) {
        const int colbase = cidx * 512 + ct * 128 + w * 32;

        // Burst all 16 B fragment loads (fully coalesced 1KB each)
        bf16x8 b[2][8];
        #pragma unroll
        for (int kk = 0; kk < 8; ++kk)
            #pragma unroll
            for (int n = 0; n < 2; ++n)
                b[n][kk] = *reinterpret_cast<const bf16x8*>(
                    reinterpret_cast<const char*>(cbf)
                    + ((colbase >> 4) + n) * 8192 + kk * 1024 + l * 16);

        // Swapped operands: acc[m][n] holds D[col][row] -> lane: row = lr (fixed),
        // cols = hk*4 + j (contiguous) -> dwordx4 stores.
        f32x4 acc[2][2] = {};
        #pragma unroll
        for (int kk = 0; kk < 8; ++kk)
            #pragma unroll
            for (int m = 0; m < 2; ++m)
                #pragma unroll
                for (int n = 0; n < 2; ++n)
                    acc[m][n] = __builtin_amdgcn_mfma_f32_16x16x32_bf16(b[n][kk], a[m][kk], acc[m][n], 0, 0, 0);

        // ---- Epilogue: out = exp(-beta*(xsq + csq - 2*cross)), 16B nt stores ----
        #pragma unroll
        for (int n = 0; n < 2; ++n) {
            const int c0 = colbase + n * 16 + hk * 4;
            const f32x4 cs = *reinterpret_cast<const f32x4*>(csq + c0);
            const f32x4 bt = *reinterpret_cast<const f32x4*>(betas + c0);
            #pragma unroll
            for (int m = 0; m < 2; ++m) {
                const float xs = (m == 0) ? xsq0 : xsq1;
                f32x4 r;
                #pragma unroll
                for (int j = 0; j < 4; ++j)
                    r[j] = __expf(-bt[j] * (xs + cs[j] - 2.0f * acc[m][n][j]));
                __builtin_nontemporal_store(
                    r, reinterpret_cast<f32x4*>(out + (size_t)(row0 + m * 16 + lr) * K_CTR + c0));
            }
        }
    }
}

extern "C" void kernel_launch(void* const* d_in, const int* in_sizes, int n_in,
                              void* d_out, int out_size, void* d_ws, size_t ws_size,
                              hipStream_t stream) {
    const float* x       = (const float*)d_in[0];
    const float* centers = (const float*)d_in[1];
    const float* betas   = (const float*)d_in[2];
    float* out = (float*)d_out;

    unsigned short* cbf = (unsigned short*)d_ws;                      // 512 KB fragment-major bf16 centers
    float* csq = (float*)((char*)d_ws + (size_t)K_CTR * D_DIM * 2);   // 4 KB c_sq

    rbf_prep<<<K_CTR / 8, 256, 0, stream>>>(centers, cbf, csq);
    rbf_main<<<(B_ROWS / BM) * CSPLIT, 256, 0, stream>>>(x, cbf, csq, betas, out);
}